// Round 6
// baseline (269.012 us; speedup 1.0000x reference)
//
#include <hip/hip_runtime.h>
#include <math.h>

#define NCELLS 1024
#define HID 512
#define ODIM 256
#define NPAIRS 512

typedef __attribute__((ext_vector_type(4))) float f32x4;
typedef __attribute__((ext_vector_type(8))) short short8;
typedef unsigned short ushort_t;

__device__ inline float sigm(float x){ return 1.0f/(1.0f + expf(-x)); }
__device__ inline float tanh3(float x){ return x*fmaf(x*x, -0.33333334f, 1.0f); }
__device__ inline ushort_t f2bf(float f){
    unsigned u = __float_as_uint(f);
    return (ushort_t)((u + 0x7FFFu + ((u>>16)&1u)) >> 16);
}
__device__ inline short8 pack8(float4 v0, float4 v1){
    short8 o;
    o[0]=(short)f2bf(v0.x); o[1]=(short)f2bf(v0.y); o[2]=(short)f2bf(v0.z); o[3]=(short)f2bf(v0.w);
    o[4]=(short)f2bf(v1.x); o[5]=(short)f2bf(v1.y); o[6]=(short)f2bf(v1.z); o[7]=(short)f2bf(v1.w);
    return o;
}

// ============ K_CVTW: weights -> bf16 fragment order ============
__global__ __launch_bounds__(256) void k_cvtw(
    const float* __restrict__ W1a, const float* __restrict__ W1g,
    const float* __restrict__ W2a, const float* __restrict__ W2g,
    const float* __restrict__ w_ih, const float* __restrict__ w_hh,
    const float* __restrict__ b1a, const float* __restrict__ b1g,
    const float* __restrict__ b2a, const float* __restrict__ b2g,
    ushort_t* __restrict__ Wc1f, ushort_t* __restrict__ Wc2f,
    ushort_t* __restrict__ wihf, ushort_t* __restrict__ whhf,
    float* __restrict__ bc1, float* __restrict__ bc2, float* __restrict__ wcol)
{
    const int t = threadIdx.x;
    if (blockIdx.x == 704){ // scalar tail: bc1(256) bc2(256) wcol(1536)
        #pragma unroll
        for (int i=0;i<8;++i){
            int id = i*256 + t;
            if (id < 256)      bc1[id] = (id<128) ? b1a[id] : b1g[id-128];
            else if (id < 512){ int k=id-256; bc2[k] = b2a[k] - b2g[k]; }
            else              { int k=id-512; wcol[k] = w_ih[(size_t)k*257 + 256]; }
        }
        return;
    }
    const int T = blockIdx.x*4 + (t>>6);
    const int lane = t & 63;
    int job, idx, KT; ushort_t* dst;
    if      (T < 384){  job=0; idx=T;      KT=24; dst=Wc1f; }
    else if (T < 512){  job=1; idx=T-384;  KT=8;  dst=Wc2f; }
    else if (T < 1280){ job=2; idx=T-512;  KT=8;  dst=wihf; }
    else             {  job=3; idx=T-1280; KT=16; dst=whhf; }
    const int rt = idx / KT, kt = idx % KT;
    const int r  = rt*16 + (lane & 15);
    const int kb = kt*32 + (lane >> 4)*8;
    float v[8];
    if (job == 0){
        const float* s = (r < 128) ? (W1a + (size_t)r*768 + kb) : (W1g + (size_t)(r-128)*768 + kb);
        #pragma unroll
        for (int j=0;j<8;++j) v[j] = s[j];
    } else if (job == 1){
        if (kb < 128){ const float* s = W2a + (size_t)r*128 + kb;
            #pragma unroll
            for (int j=0;j<8;++j) v[j] = s[j];
        } else { const float* s = W2g + (size_t)r*128 + (kb-128);
            #pragma unroll
            for (int j=0;j<8;++j) v[j] = -s[j];
        }
    } else if (job == 2){
        const float* s = w_ih + (size_t)r*257 + kb;
        #pragma unroll
        for (int j=0;j<8;++j) v[j] = s[j];
    } else {
        const float* s = w_hh + (size_t)r*512 + kb;
        #pragma unroll
        for (int j=0;j<8;++j) v[j] = s[j];
    }
    short8 o;
    #pragma unroll
    for (int j=0;j<8;++j) o[j] = (short)f2bf(v[j]);
    ((short8*)dst)[(size_t)idx*64 + lane] = o;
}

// ============ K_FWD: fused MLP + GRU-gate GEMMs ============
// grid (6,64), 256 thr. blockIdx.y = 16-row tile; blockIdx.x = gate-group sextant.
// Every block recomputes the cheap MLP (128 MFMA); each wave then computes
// exactly ONE 4-tile gate group (96 MFMA). blockIdx.x==0 also writes OUT/tension.
__global__ __launch_bounds__(256) void k_fwd(
    const float* __restrict__ x, const float* __restrict__ hiddens,
    const ushort_t* __restrict__ Wc1f, const ushort_t* __restrict__ Wc2f,
    const ushort_t* __restrict__ wihf, const ushort_t* __restrict__ whhf,
    const float* __restrict__ bc1, const float* __restrict__ bc2,
    const float* __restrict__ b_ih, const float* __restrict__ b_hh,
    float* __restrict__ OUT, float* __restrict__ tension,
    float* __restrict__ GS, float* __restrict__ GIn, float* __restrict__ GHn)
{
    const int r0 = blockIdx.y*16;
    const int t = threadIdx.x;
    const int lane = t & 63, w = t >> 6;
    __shared__ short8 lds_comb[24*64];
    __shared__ short8 lds_h1[8*64];
    __shared__ short8 lds_of[8*64];
    __shared__ __align__(16) float lds_tile[16][264];
    const short8* B1 = (const short8*)Wc1f;
    const short8* B2 = (const short8*)Wc2f;
    const short8* Bi = (const short8*)wihf;
    const short8* Bh = (const short8*)whhf;

    // ---- phase 0: comb frags
    #pragma unroll
    for (int s6=0; s6<6; ++s6){
        int s = t + s6*256;
        int kt = s>>6, ln = s&63;
        int row = r0 + (ln&15);
        int cb = kt*32 + ((ln>>4)<<3);
        const float* src = (cb < 256) ? (x + cb) : (hiddens + (size_t)row*HID + (cb-256));
        float4 v0 = *(const float4*)src;
        float4 v1 = *(const float4*)(src+4);
        lds_comb[s] = pack8(v0, v1);
    }
    __syncthreads();

    // ---- phase 1: L1 = relu(comb @ Wc1^T + bc1)
    {
        f32x4 acc[4] = {{0,0,0,0},{0,0,0,0},{0,0,0,0},{0,0,0,0}};
        for (int kt=0; kt<24; ++kt){
            short8 a = lds_comb[kt*64 + lane];
            #pragma unroll
            for (int c=0;c<4;++c){
                short8 b = B1[((w*4+c)*24 + kt)*64 + lane];
                acc[c] = __builtin_amdgcn_mfma_f32_16x16x32_bf16(a, b, acc[c], 0,0,0);
            }
        }
        const int rb = (lane>>4)*4;
        #pragma unroll
        for (int c=0;c<4;++c){
            int col = w*64 + c*16 + (lane&15);
            float bb = bc1[col];
            #pragma unroll
            for (int i=0;i<4;++i)
                lds_tile[rb+i][col] = fmaxf(acc[c][i] + bb, 0.f);
        }
    }
    __syncthreads();
    // ---- phase 2: H1 -> frags
    #pragma unroll
    for (int s2=0; s2<2; ++s2){
        int s = t + s2*256;
        int ln = s&63;
        int row = ln&15, cb = (s>>6)*32 + ((ln>>4)<<3);
        float4 v0 = *(const float4*)&lds_tile[row][cb];
        float4 v1 = *(const float4*)&lds_tile[row][cb+4];
        lds_h1[s] = pack8(v0, v1);
    }
    __syncthreads();
    // ---- phase 3: L2 = H1 @ Wc2^T + bc2
    {
        f32x4 acc[4] = {{0,0,0,0},{0,0,0,0},{0,0,0,0},{0,0,0,0}};
        for (int kt=0; kt<8; ++kt){
            short8 a = lds_h1[kt*64 + lane];
            #pragma unroll
            for (int c=0;c<4;++c){
                short8 b = B2[((w*4+c)*8 + kt)*64 + lane];
                acc[c] = __builtin_amdgcn_mfma_f32_16x16x32_bf16(a, b, acc[c], 0,0,0);
            }
        }
        const int rb = (lane>>4)*4;
        #pragma unroll
        for (int c=0;c<4;++c){
            int col = w*64 + c*16 + (lane&15);
            float bb = bc2[col];
            #pragma unroll
            for (int i=0;i<4;++i)
                lds_tile[rb+i][col] = acc[c][i] + bb;
        }
    }
    __syncthreads();
    // ---- phase 4a: tension (x==0 blocks only)
    if (blockIdx.x == 0){
        int row = t>>4, seg = t&15;
        float s = 0.f;
        #pragma unroll
        for (int c=0;c<16;++c){ float v = lds_tile[row][seg*16+c]; s = fmaf(v,v,s); }
        s += __shfl_xor(s,1); s += __shfl_xor(s,2); s += __shfl_xor(s,4); s += __shfl_xor(s,8);
        if (seg == 0) tension[r0+row] = s * (1.0f/ODIM);
        // ---- phase 4b: OUT f32
        #pragma unroll
        for (int s4=0; s4<4; ++s4){
            int ss = t + s4*256;
            int rr = ss>>6, c4 = ss&63;
            float4 v = *(const float4*)&lds_tile[rr][c4*4];
            *(float4*)&OUT[(size_t)(r0+rr)*ODIM + c4*4] = v;
        }
    }
    // ---- phase 4c: Of frags (all blocks — A-operand for gate GEMM)
    #pragma unroll
    for (int s2=0; s2<2; ++s2){
        int s = t + s2*256;
        int ln = s&63;
        int row = ln&15, cb = (s>>6)*32 + ((ln>>4)<<3);
        float4 v0 = *(const float4*)&lds_tile[row][cb];
        float4 v1 = *(const float4*)&lds_tile[row][cb+4];
        lds_of[s] = pack8(v0, v1);
    }
    __syncthreads();
    // ---- phase 5: this wave's single gate group (4 n-tiles)
    const int rb = (lane>>4)*4;
    const int g = blockIdx.x*4 + w;      // 0..23
    const int nt0 = g*4;                 // of 96 n-tiles
    if (nt0 < 64){
        f32x4 acc[4] = {{0,0,0,0},{0,0,0,0},{0,0,0,0},{0,0,0,0}};
        for (int kt=0; kt<8; ++kt){
            short8 a = lds_of[kt*64 + lane];
            #pragma unroll
            for (int c=0;c<4;++c){
                short8 b = Bi[((nt0+c)*8 + kt)*64 + lane];
                acc[c] = __builtin_amdgcn_mfma_f32_16x16x32_bf16(a, b, acc[c], 0,0,0);
            }
        }
        for (int kt=0; kt<16; ++kt){
            short8 a = lds_comb[(8+kt)*64 + lane];
            #pragma unroll
            for (int c=0;c<4;++c){
                short8 b = Bh[((nt0+c)*16 + kt)*64 + lane];
                acc[c] = __builtin_amdgcn_mfma_f32_16x16x32_bf16(a, b, acc[c], 0,0,0);
            }
        }
        #pragma unroll
        for (int c=0;c<4;++c){
            int n = (nt0+c)*16 + (lane&15);
            float bb = b_ih[n] + b_hh[n];
            #pragma unroll
            for (int i=0;i<4;++i)
                GS[(size_t)(r0+rb+i)*1024 + n] = acc[c][i] + bb;
        }
    } else {
        f32x4 ai[4] = {{0,0,0,0},{0,0,0,0},{0,0,0,0},{0,0,0,0}};
        f32x4 ah[4] = {{0,0,0,0},{0,0,0,0},{0,0,0,0},{0,0,0,0}};
        for (int kt=0; kt<8; ++kt){
            short8 a = lds_of[kt*64 + lane];
            #pragma unroll
            for (int c=0;c<4;++c){
                short8 b = Bi[((nt0+c)*8 + kt)*64 + lane];
                ai[c] = __builtin_amdgcn_mfma_f32_16x16x32_bf16(a, b, ai[c], 0,0,0);
            }
        }
        for (int kt=0; kt<16; ++kt){
            short8 a = lds_comb[(8+kt)*64 + lane];
            #pragma unroll
            for (int c=0;c<4;++c){
                short8 b = Bh[((nt0+c)*16 + kt)*64 + lane];
                ah[c] = __builtin_amdgcn_mfma_f32_16x16x32_bf16(a, b, ah[c], 0,0,0);
            }
        }
        #pragma unroll
        for (int c=0;c<4;++c){
            int j = (nt0+c-64)*16 + (lane&15);
            float bi = b_ih[1024+j], bh = b_hh[1024+j];
            #pragma unroll
            for (int i=0;i<4;++i){
                GIn[(size_t)(r0+rb+i)*HID + j] = ai[c][i] + bi;
                GHn[(size_t)(r0+rb+i)*HID + j] = ah[c][i] + bh;
            }
        }
    }
}

// ============ fused GRU + pair entanglement mixing ============
__global__ __launch_bounds__(512) void k_mix(const float* __restrict__ GS,
        const float* __restrict__ GIn, const float* __restrict__ GHn,
        const float* __restrict__ tension, const float* __restrict__ wcol,
        const float* __restrict__ hiddens,
        const float* __restrict__ bell, const float* __restrict__ ent,
        float* __restrict__ hmix)
{
    const int p = blockIdx.x;
    const int tid = threadIdx.x;
    const int lane = tid & 63;
    const int wv = tid >> 6;
    __shared__ __align__(16) float hi[HID], hj[HID];
    __shared__ __align__(16) float colacc[8][HID];
    {
        const int j = tid;
        const float wj0 = wcol[j], wj1 = wcol[512+j], wj2 = wcol[1024+j];
        #pragma unroll
        for (int c01=0; c01<2; ++c01){
            const int cell = 2*p + c01;
            const float tv = tension[cell];
            const float* gs = GS + (size_t)cell*1024;
            float rg = sigm(gs[j]     + tv*wj0);
            float zg = sigm(gs[512+j] + tv*wj1);
            float nn = tanhf(GIn[(size_t)cell*HID + j] + tv*wj2 + rg*GHn[(size_t)cell*HID + j]);
            float h  = (1.f - zg)*nn + zg*hiddens[(size_t)cell*HID + j];
            (c01 ? hj : hi)[j] = h;
        }
    }
    __syncthreads();
    const float* __restrict__ rot = bell + (size_t)p * HID * HID;
    const float e = 1.0f/(1.0f + expf(-ent[p]));
    const float one_e = 1.0f - e;
    const int c0 = lane<<2, c1 = 256 + (lane<<2);
    float hjr[8];
    #pragma unroll
    for (int k=0;k<4;++k){ hjr[k]=hj[c0+k]; hjr[4+k]=hj[c1+k]; }
    float aj[8] = {};
    // 2-row interleave: rows r and r+8 per iteration (4 loads + 2 indep reduces in flight)
    for (int r = wv; r < HID; r += 16) {
        const float* row0 = rot + (size_t)r*HID;
        const float* row1 = rot + (size_t)(r+8)*HID;
        float4 a0 = *(const float4*)(row0 + c0);
        float4 a1 = *(const float4*)(row0 + c1);
        float4 b0 = *(const float4*)(row1 + c0);
        float4 b1 = *(const float4*)(row1 + c1);
        float t0[8], t1[8];
        t0[0]=tanh3(a0.x); t0[1]=tanh3(a0.y); t0[2]=tanh3(a0.z); t0[3]=tanh3(a0.w);
        t0[4]=tanh3(a1.x); t0[5]=tanh3(a1.y); t0[6]=tanh3(a1.z); t0[7]=tanh3(a1.w);
        t1[0]=tanh3(b0.x); t1[1]=tanh3(b0.y); t1[2]=tanh3(b0.z); t1[3]=tanh3(b0.w);
        t1[4]=tanh3(b1.x); t1[5]=tanh3(b1.y); t1[6]=tanh3(b1.z); t1[7]=tanh3(b1.w);
        const float hir0 = hi[r], hir1 = hi[r+8];
        float rp0 = 0.0f, rp1 = 0.0f;
        #pragma unroll
        for (int k=0;k<8;++k){
            rp0 = fmaf(t0[k], hjr[k], rp0);
            rp1 = fmaf(t1[k], hjr[k], rp1);
            aj[k] = fmaf(t0[k], hir0, fmaf(t1[k], hir1, aj[k]));
        }
        #pragma unroll
        for (int m=1;m<64;m<<=1){ rp0 += __shfl_xor(rp0, m); rp1 += __shfl_xor(rp1, m); }
        if (lane == 0){
            hmix[(size_t)(2*p)*HID + r]   = one_e*hir0 + e*rp0;
            hmix[(size_t)(2*p)*HID + r+8] = one_e*hir1 + e*rp1;
        }
    }
    *(float4*)&colacc[wv][c0] = make_float4(aj[0],aj[1],aj[2],aj[3]);
    *(float4*)&colacc[wv][c1] = make_float4(aj[4],aj[5],aj[6],aj[7]);
    __syncthreads();
    float s = 0.0f;
    #pragma unroll
    for (int w=0;w<8;++w) s += colacc[w][tid];
    hmix[(size_t)(2*p+1)*HID + tid] = -(one_e*hj[tid] + e*s);
}

// ============ faction mean (32 blocks x 128 thr) ============
__global__ __launch_bounds__(128) void k_fmean(const float* __restrict__ hmix, float* __restrict__ fmean){
    int f = blockIdx.x >> 2;
    int d = (blockIdx.x & 3)*128 + threadIdx.x;
    float s = 0.0f;
    for (int c=0;c<128;++c) s += hmix[(size_t)((f<<7)+c)*HID + d];
    fmean[f*HID + d] = s*(1.0f/128.0f);
}

// ============ faction sync + debate ============
__global__ __launch_bounds__(512) void k_final_h(const float* __restrict__ hmix,
        const float* __restrict__ fmean, const int* __restrict__ stepp, float* __restrict__ hout){
    int cell = blockIdx.x, d = threadIdx.x;
    int f = cell >> 7;
    float v = 0.85f*hmix[(size_t)cell*HID + d] + 0.15f*fmean[f*HID + d];
    if (*stepp > 5 && (cell & 127) < 32){
        float g = 0.0f;
        #pragma unroll
        for (int q=0;q<8;++q) g += fmean[q*HID + d];
        g *= 0.125f;
        v = 0.85f*v + 0.15f*g;
    }
    hout[(size_t)cell*HID + d] = v;
}

// ============ fused tail: softmax + weighted rowsum + head (1 block) ============
__global__ __launch_bounds__(1024) void k_tail(const float* __restrict__ tension,
        const float* __restrict__ OUT, const float* __restrict__ head_w,
        const float* __restrict__ head_b, float* __restrict__ out)
{
    const int t = threadIdx.x;
    const int lane = t & 63, wv = t >> 6;
    __shared__ float red[16], redb[16], SS[2];
    __shared__ float wts[1024];
    __shared__ __align__(16) float cop[4][256];
    __shared__ __align__(16) float co[256];
    float tv = tension[t];
    float m = tv;
    #pragma unroll
    for (int s=1;s<64;s<<=1) m = fmaxf(m, __shfl_xor(m, s));
    if (lane==0) red[wv] = m;
    __syncthreads();
    if (t==0){ float mm=red[0]; for(int i=1;i<16;++i) mm=fmaxf(mm,red[i]); SS[1]=mm; }
    __syncthreads();
    float ex = expf(tv - SS[1]);
    float s2 = ex, s3 = tv;
    #pragma unroll
    for (int s=1;s<64;s<<=1){ s2 += __shfl_xor(s2,s); s3 += __shfl_xor(s3,s); }
    if (lane==0){ red[wv]=s2; redb[wv]=s3; }
    __syncthreads();
    if (t==0){
        float a=0,b=0;
        for(int i=0;i<16;++i){ a+=red[i]; b+=redb[i]; }
        SS[0]=a;
        out[256] = b*(1.0f/1024.0f);   // avg_tension
    }
    __syncthreads();
    wts[t] = ex / SS[0];
    __syncthreads();
    // weighted row-sum: quarter q sums 256 rows for its column c
    {
        const int q = t >> 8, c = t & 255;
        float s = 0.0f;
        for (int r = q*256; r < q*256+256; ++r)
            s = fmaf(wts[r], OUT[(size_t)r*ODIM + c], s);
        cop[q][c] = s;
    }
    __syncthreads();
    if (t < 256) co[t] = cop[0][t] + cop[1][t] + cop[2][t] + cop[3][t];
    __syncthreads();
    if (t < 256){
        float acc = head_b[t];
        const float4* wr = (const float4*)(head_w + (size_t)t*ODIM);
        #pragma unroll 4
        for (int c4=0;c4<64;++c4){
            float4 w4 = wr[c4];
            acc = fmaf(w4.x, co[c4*4+0], acc);
            acc = fmaf(w4.y, co[c4*4+1], acc);
            acc = fmaf(w4.z, co[c4*4+2], acc);
            acc = fmaf(w4.w, co[c4*4+3], acc);
        }
        out[t] = acc;                  // pred
    }
}

extern "C" void kernel_launch(void* const* d_in, const int* in_sizes, int n_in,
                              void* d_out, int out_size, void* d_ws, size_t ws_size,
                              hipStream_t stream)
{
    const float* x      = (const float*)d_in[0];
    const float* hiddens= (const float*)d_in[1];
    const float* W1a=(const float*)d_in[2];  const float* b1a=(const float*)d_in[3];
    const float* W2a=(const float*)d_in[4];  const float* b2a=(const float*)d_in[5];
    const float* W1g=(const float*)d_in[6];  const float* b1g=(const float*)d_in[7];
    const float* W2g=(const float*)d_in[8];  const float* b2g=(const float*)d_in[9];
    const float* w_ih=(const float*)d_in[10]; const float* w_hh=(const float*)d_in[11];
    const float* b_ih=(const float*)d_in[12]; const float* b_hh=(const float*)d_in[13];
    const float* head_w=(const float*)d_in[14]; const float* head_b=(const float*)d_in[15];
    const float* ent=(const float*)d_in[16]; const float* bell=(const float*)d_in[17];
    const int*   stepp=(const int*)d_in[18];
    float* out = (float*)d_out;

    char* wsb = (char*)d_ws;
    size_t off = 0;
    auto carve = [&](size_t bytes)->char*{ char* p = wsb + off; off += (bytes + 63) & ~(size_t)63; return p; };
    ushort_t* Wc1f  = (ushort_t*)carve((size_t)256*768*2);
    ushort_t* Wc2f  = (ushort_t*)carve((size_t)256*256*2);
    ushort_t* wihf  = (ushort_t*)carve((size_t)1536*256*2);
    ushort_t* whhf  = (ushort_t*)carve((size_t)1536*512*2);
    float* bc1   = (float*)carve(256*4);
    float* bc2   = (float*)carve(256*4);
    float* wcol  = (float*)carve(1536*4);
    float* OUT   = (float*)carve((size_t)1024*256*4);
    float* tension=(float*)carve(1024*4);
    float* GS    = (float*)carve((size_t)1024*1024*4);
    float* GIn   = (float*)carve((size_t)1024*512*4);
    float* GHn   = (float*)carve((size_t)1024*512*4);
    float* hmix  = (float*)carve((size_t)1024*512*4);
    float* fmean = (float*)carve(8*512*4);

    k_cvtw<<<705, 256, 0, stream>>>(W1a, W1g, W2a, W2g, w_ih, w_hh,
                                    b1a, b1g, b2a, b2g,
                                    Wc1f, Wc2f, wihf, whhf, bc1, bc2, wcol);
    k_fwd<<<dim3(6,64), 256, 0, stream>>>(x, hiddens, Wc1f, Wc2f, wihf, whhf,
                                  bc1, bc2, b_ih, b_hh,
                                  OUT, tension, GS, GIn, GHn);
    k_mix<<<512, 512, 0, stream>>>(GS, GIn, GHn, tension, wcol, hiddens, bell, ent, hmix);
    k_fmean<<<32, 128, 0, stream>>>(hmix, fmean);
    k_final_h<<<1024, 512, 0, stream>>>(hmix, fmean, stepp, out + 257);
    k_tail<<<1, 1024, 0, stream>>>(tension, OUT, head_w, head_b, out);
}

// Round 7
// 165.073 us; speedup vs baseline: 1.6297x; 1.6297x over previous
//
#include <hip/hip_runtime.h>
#include <math.h>

#define NCELLS 1024
#define HID 512
#define ODIM 256
#define NPAIRS 512

typedef __attribute__((ext_vector_type(4))) float f32x4;
typedef __attribute__((ext_vector_type(8))) short short8;
typedef unsigned short ushort_t;

__device__ inline float sigm(float x){ return 1.0f/(1.0f + expf(-x)); }
__device__ inline float tanh3(float x){ return x*fmaf(x*x, -0.33333334f, 1.0f); }
__device__ inline ushort_t f2bf(float f){
    unsigned u = __float_as_uint(f);
    return (ushort_t)((u + 0x7FFFu + ((u>>16)&1u)) >> 16);
}

// ============ K_CVT: build bf16 fragment-order operands ============
__global__ __launch_bounds__(64) void k_cvt(
    const float* __restrict__ x, const float* __restrict__ hiddens,
    const float* __restrict__ W1a, const float* __restrict__ W1g,
    const float* __restrict__ W2a, const float* __restrict__ W2g,
    const float* __restrict__ w_ih, const float* __restrict__ w_hh,
    const float* __restrict__ b1a, const float* __restrict__ b1g,
    const float* __restrict__ b2a, const float* __restrict__ b2g,
    ushort_t* __restrict__ Wc1f, ushort_t* __restrict__ Wc2f,
    ushort_t* __restrict__ wihf, ushort_t* __restrict__ whhf,
    ushort_t* __restrict__ combf, ushort_t* __restrict__ hiddf,
    float* __restrict__ bc1, float* __restrict__ bc2, float* __restrict__ wcol)
{
    const int b = blockIdx.x;
    const int lane = threadIdx.x;
    if (b >= 5376){ // tail: scalar jobs
        int t = (b - 5376)*64 + lane;
        if (t < 256)       bc1[t] = (t<128) ? b1a[t] : b1g[t-128];
        else if (t < 512)  { int i=t-256; bc2[i] = b2a[i] - b2g[i]; }
        else               { int i=t-512; wcol[i] = w_ih[(size_t)i*257 + 256]; }
        return;
    }
    int job, idx, KT; ushort_t* dst;
    if      (b < 384){  job=0; idx=b;      KT=24; dst=Wc1f; }
    else if (b < 512){  job=1; idx=b-384;  KT=8;  dst=Wc2f; }
    else if (b < 1280){ job=2; idx=b-512;  KT=8;  dst=wihf; }
    else if (b < 2816){ job=3; idx=b-1280; KT=16; dst=whhf; }
    else if (b < 4352){ job=4; idx=b-2816; KT=24; dst=combf;}
    else             {  job=5; idx=b-4352; KT=16; dst=hiddf;}
    const int rt = idx / KT, kt = idx % KT;
    const int r  = rt*16 + (lane & 15);
    const int kb = kt*32 + (lane >> 4)*8;
    float v[8];
    if (job == 0){
        const float* s = (r < 128) ? (W1a + (size_t)r*768) : (W1g + (size_t)(r-128)*768);
        #pragma unroll
        for (int j=0;j<8;++j) v[j] = s[kb+j];
    } else if (job == 1){
        if (kb < 128){ const float* s = W2a + (size_t)r*128 + kb;
            #pragma unroll
            for (int j=0;j<8;++j) v[j] = s[j];
        } else { const float* s = W2g + (size_t)r*128 + (kb-128);
            #pragma unroll
            for (int j=0;j<8;++j) v[j] = -s[j];
        }
    } else if (job == 2){
        const float* s = w_ih + (size_t)r*257 + kb;
        #pragma unroll
        for (int j=0;j<8;++j) v[j] = s[j];
    } else if (job == 3){
        const float* s = w_hh + (size_t)r*512 + kb;
        #pragma unroll
        for (int j=0;j<8;++j) v[j] = s[j];
    } else if (job == 4){
        if (kb < 256){
            #pragma unroll
            for (int j=0;j<8;++j) v[j] = x[kb+j];
        } else { const float* s = hiddens + (size_t)r*512 + (kb-256);
            #pragma unroll
            for (int j=0;j<8;++j) v[j] = s[j];
        }
    } else {
        const float* s = hiddens + (size_t)r*512 + kb;
        #pragma unroll
        for (int j=0;j<8;++j) v[j] = s[j];
    }
    short8 o;
    #pragma unroll
    for (int j=0;j<8;++j) o[j] = (short)f2bf(v[j]);
    ((short8*)dst)[(size_t)idx*64 + lane] = o;
}

// ============ MFMA GEMM: C[M x N] = A @ W^T + bias ============
template<int KT, int EPI>
__global__ __launch_bounds__(256) void k_mm(
    const ushort_t* __restrict__ Af, const ushort_t* __restrict__ Bf,
    const float* __restrict__ bias, float* __restrict__ C,
    ushort_t* __restrict__ Cf, int N)
{
    const int lane = threadIdx.x & 63;
    const int w    = threadIdx.x >> 6;
    const int mtile = blockIdx.y*4 + w;
    const int nt0   = blockIdx.x*2;
    const short8* A8 = (const short8*)Af;
    const short8* B8 = (const short8*)Bf;
    f32x4 acc0 = {0.f,0.f,0.f,0.f}, acc1 = {0.f,0.f,0.f,0.f};
    #pragma unroll 4
    for (int kt=0; kt<KT; ++kt){
        short8 a  = A8[((size_t)mtile*KT + kt)*64 + lane];
        short8 b0 = B8[((size_t)nt0*KT + kt)*64 + lane];
        short8 b1 = B8[((size_t)(nt0+1)*KT + kt)*64 + lane];
        acc0 = __builtin_amdgcn_mfma_f32_16x16x32_bf16(a, b0, acc0, 0,0,0);
        acc1 = __builtin_amdgcn_mfma_f32_16x16x32_bf16(a, b1, acc1, 0,0,0);
    }
    if (EPI == 0){
        const int r0 = mtile*16 + (lane>>4)*4;
        const int c0 = nt0*16 + (lane&15);
        const float bb0 = bias[c0], bb1 = bias[c0+16];
        #pragma unroll
        for (int i=0;i<4;++i){
            C[(size_t)(r0+i)*N + c0]    = acc0[i] + bb0;
            C[(size_t)(r0+i)*N + c0+16] = acc1[i] + bb1;
        }
    } else {
        __shared__ float lt[4][16][33];
        const int rr = (lane>>4)*4, cc = lane&15;
        const float bb0 = bias[nt0*16 + cc], bb1 = bias[nt0*16 + 16 + cc];
        #pragma unroll
        for (int i=0;i<4;++i){
            lt[w][rr+i][cc]    = fmaxf(acc0[i] + bb0, 0.f);
            lt[w][rr+i][16+cc] = fmaxf(acc1[i] + bb1, 0.f);
        }
        __syncthreads();
        const int m = lane & 15, kb = (lane>>4)*8;
        short8 o;
        #pragma unroll
        for (int j=0;j<8;++j) o[j] = (short)f2bf(lt[w][m][kb+j]);
        ((short8*)Cf)[((size_t)mtile*gridDim.x + blockIdx.x)*64 + lane] = o;
    }
}

// ============ tension + OUT -> bf16 A-frag ============
__global__ __launch_bounds__(512) void k_tension_cvt(const float* __restrict__ OUT,
        float* __restrict__ tension, ushort_t* __restrict__ Of)
{
    const int mt = blockIdx.x;
    const int lane = threadIdx.x & 63, wv = threadIdx.x >> 6; // wv = ktile (8)
    const int m = mt*16 + (lane&15);
    const int k = wv*32 + (lane>>4)*8;
    const float* p = OUT + (size_t)m*ODIM + k;
    float4 v0 = *(const float4*)p;
    float4 v1 = *(const float4*)(p+4);
    float s = v0.x*v0.x + v0.y*v0.y + v0.z*v0.z + v0.w*v0.w
            + v1.x*v1.x + v1.y*v1.y + v1.z*v1.z + v1.w*v1.w;
    short8 o;
    o[0]=(short)f2bf(v0.x); o[1]=(short)f2bf(v0.y); o[2]=(short)f2bf(v0.z); o[3]=(short)f2bf(v0.w);
    o[4]=(short)f2bf(v1.x); o[5]=(short)f2bf(v1.y); o[6]=(short)f2bf(v1.z); o[7]=(short)f2bf(v1.w);
    ((short8*)Of)[((size_t)mt*8 + wv)*64 + lane] = o;
    s += __shfl_xor(s, 16); s += __shfl_xor(s, 32);
    __shared__ float red[8][16];
    if (lane < 16) red[wv][lane] = s;
    __syncthreads();
    if (threadIdx.x < 16){
        float t = 0.f;
        #pragma unroll
        for (int q=0;q<8;++q) t += red[q][threadIdx.x];
        tension[mt*16 + threadIdx.x] = t * (1.0f/ODIM);
    }
}

// ============ fused GRU + pair entanglement mixing ============
// 4-row-deep load pipeline: 8 float4 loads issued per body, x2 unroll.
__global__ __launch_bounds__(512) void k_mix(const float* __restrict__ GI,
        const float* __restrict__ GH, const float* __restrict__ tension,
        const float* __restrict__ wcol, const float* __restrict__ hiddens,
        const float* __restrict__ bell, const float* __restrict__ ent,
        float* __restrict__ hmix)
{
    const int p = blockIdx.x;
    const int tid = threadIdx.x;
    const int lane = tid & 63;
    const int wv = tid >> 6;
    __shared__ __align__(16) float hi[HID], hj[HID];
    __shared__ __align__(16) float colacc[8][HID];
    // GRU epilogue for cells 2p (->hi), 2p+1 (->hj)
    {
        const int j = tid;
        const float wj0 = wcol[j], wj1 = wcol[512+j], wj2 = wcol[1024+j];
        #pragma unroll
        for (int c01=0; c01<2; ++c01){
            const int cell = 2*p + c01;
            const float tv = tension[cell];
            const float* gi = GI + (size_t)cell*1536;
            const float* gh = GH + (size_t)cell*1536;
            float rg = sigm(gi[j]      + tv*wj0 + gh[j]);
            float zg = sigm(gi[512+j]  + tv*wj1 + gh[512+j]);
            float nn = tanhf(gi[1024+j]+ tv*wj2 + rg*gh[1024+j]);
            float h  = (1.f - zg)*nn + zg*hiddens[(size_t)cell*HID + j];
            (c01 ? hj : hi)[j] = h;
        }
    }
    __syncthreads();
    const float* __restrict__ rot = bell + (size_t)p * HID * HID;
    const float e = 1.0f/(1.0f + expf(-ent[p]));
    const float one_e = 1.0f - e;
    const int c0 = lane<<2, c1 = 256 + (lane<<2);
    float hjr[8];
    #pragma unroll
    for (int k=0;k<4;++k){ hjr[k]=hj[c0+k]; hjr[4+k]=hj[c1+k]; }
    float aj[8] = {};
    #pragma unroll 2
    for (int r = wv; r < HID; r += 32) {
        // issue all 8 loads (4 rows x 2 halves) before any use
        const float* rp0 = rot + (size_t)r*HID;
        const float* rp1 = rot + (size_t)(r+8)*HID;
        const float* rp2 = rot + (size_t)(r+16)*HID;
        const float* rp3 = rot + (size_t)(r+24)*HID;
        float4 a0 = *(const float4*)(rp0 + c0);
        float4 a1 = *(const float4*)(rp0 + c1);
        float4 b0 = *(const float4*)(rp1 + c0);
        float4 b1 = *(const float4*)(rp1 + c1);
        float4 g0 = *(const float4*)(rp2 + c0);
        float4 g1 = *(const float4*)(rp2 + c1);
        float4 d0 = *(const float4*)(rp3 + c0);
        float4 d1 = *(const float4*)(rp3 + c1);
        float t0[8], t1[8], t2[8], t3[8];
        t0[0]=tanh3(a0.x); t0[1]=tanh3(a0.y); t0[2]=tanh3(a0.z); t0[3]=tanh3(a0.w);
        t0[4]=tanh3(a1.x); t0[5]=tanh3(a1.y); t0[6]=tanh3(a1.z); t0[7]=tanh3(a1.w);
        t1[0]=tanh3(b0.x); t1[1]=tanh3(b0.y); t1[2]=tanh3(b0.z); t1[3]=tanh3(b0.w);
        t1[4]=tanh3(b1.x); t1[5]=tanh3(b1.y); t1[6]=tanh3(b1.z); t1[7]=tanh3(b1.w);
        t2[0]=tanh3(g0.x); t2[1]=tanh3(g0.y); t2[2]=tanh3(g0.z); t2[3]=tanh3(g0.w);
        t2[4]=tanh3(g1.x); t2[5]=tanh3(g1.y); t2[6]=tanh3(g1.z); t2[7]=tanh3(g1.w);
        t3[0]=tanh3(d0.x); t3[1]=tanh3(d0.y); t3[2]=tanh3(d0.z); t3[3]=tanh3(d0.w);
        t3[4]=tanh3(d1.x); t3[5]=tanh3(d1.y); t3[6]=tanh3(d1.z); t3[7]=tanh3(d1.w);
        const float h0 = hi[r], h1 = hi[r+8], h2 = hi[r+16], h3 = hi[r+24];
        float rp_0 = 0.f, rp_1 = 0.f, rp_2 = 0.f, rp_3 = 0.f;
        #pragma unroll
        for (int k=0;k<8;++k){
            rp_0 = fmaf(t0[k], hjr[k], rp_0);
            rp_1 = fmaf(t1[k], hjr[k], rp_1);
            rp_2 = fmaf(t2[k], hjr[k], rp_2);
            rp_3 = fmaf(t3[k], hjr[k], rp_3);
            aj[k] = fmaf(t0[k], h0, fmaf(t1[k], h1, fmaf(t2[k], h2, fmaf(t3[k], h3, aj[k]))));
        }
        #pragma unroll
        for (int m=1;m<64;m<<=1){
            rp_0 += __shfl_xor(rp_0, m);
            rp_1 += __shfl_xor(rp_1, m);
            rp_2 += __shfl_xor(rp_2, m);
            rp_3 += __shfl_xor(rp_3, m);
        }
        if (lane == 0){
            float* dst = hmix + (size_t)(2*p)*HID;
            dst[r]    = one_e*h0 + e*rp_0;
            dst[r+8]  = one_e*h1 + e*rp_1;
            dst[r+16] = one_e*h2 + e*rp_2;
            dst[r+24] = one_e*h3 + e*rp_3;
        }
    }
    *(float4*)&colacc[wv][c0] = make_float4(aj[0],aj[1],aj[2],aj[3]);
    *(float4*)&colacc[wv][c1] = make_float4(aj[4],aj[5],aj[6],aj[7]);
    __syncthreads();
    float s = 0.0f;
    #pragma unroll
    for (int w=0;w<8;++w) s += colacc[w][tid];
    hmix[(size_t)(2*p+1)*HID + tid] = -(one_e*hj[tid] + e*s);
}

// ============ faction mean ============
__global__ __launch_bounds__(512) void k_fmean(const float* __restrict__ hmix, float* __restrict__ fmean){
    int f = blockIdx.x, d = threadIdx.x;
    float s = 0.0f;
    for (int c=0;c<128;++c) s += hmix[(size_t)((f<<7)+c)*HID + d];
    fmean[f*HID + d] = s*(1.0f/128.0f);
}

// ============ faction sync + debate ============
__global__ __launch_bounds__(512) void k_final_h(const float* __restrict__ hmix,
        const float* __restrict__ fmean, const int* __restrict__ stepp, float* __restrict__ hout){
    int cell = blockIdx.x, d = threadIdx.x;
    int f = cell >> 7;
    float v = 0.85f*hmix[(size_t)cell*HID + d] + 0.15f*fmean[f*HID + d];
    if (*stepp > 5 && (cell & 127) < 32){
        float g = 0.0f;
        #pragma unroll
        for (int q=0;q<8;++q) g += fmean[q*HID + d];
        g *= 0.125f;
        v = 0.85f*v + 0.15f*g;
    }
    hout[(size_t)cell*HID + d] = v;
}

// ============ softmax(tension) + avg ============
__global__ __launch_bounds__(1024) void k_softmax(const float* __restrict__ tension,
        float* __restrict__ weights, float* __restrict__ avg_out){
    int t = threadIdx.x;
    int lane = t & 63, wv = t >> 6;
    float tv = tension[t];
    __shared__ float red[16], redb[16], SS[2];
    float m = tv;
    #pragma unroll
    for (int s=1;s<64;s<<=1) m = fmaxf(m, __shfl_xor(m, s));
    if (lane==0) red[wv] = m;
    __syncthreads();
    if (t==0){ float mm=red[0]; for(int i=1;i<16;++i) mm=fmaxf(mm,red[i]); SS[1]=mm; }
    __syncthreads();
    float M = SS[1];
    float ex = expf(tv - M);
    float s2 = ex, s3 = tv;
    #pragma unroll
    for (int s=1;s<64;s<<=1){ s2 += __shfl_xor(s2,s); s3 += __shfl_xor(s3,s); }
    if (lane==0){ red[wv]=s2; redb[wv]=s3; }
    __syncthreads();
    if (t==0){
        float a=0,b=0;
        for(int i=0;i<16;++i){ a+=red[i]; b+=redb[i]; }
        SS[0]=a;
        avg_out[0] = b*(1.0f/1024.0f);
    }
    __syncthreads();
    weights[t] = ex / SS[0];
}

// ============ weighted row-sum partials ============
__global__ __launch_bounds__(256) void k_copart(const float* __restrict__ OUT,
        const float* __restrict__ weights, float* __restrict__ copart){
    int b = blockIdx.x, c = threadIdx.x;
    float s = 0.0f;
    for (int r = b*32; r < b*32+32; ++r) s = fmaf(weights[r], OUT[(size_t)r*ODIM + c], s);
    copart[b*ODIM + c] = s;
}

// ============ head ============
__global__ __launch_bounds__(256) void k_pred(const float* __restrict__ copart,
        const float* __restrict__ head_w, const float* __restrict__ head_b, float* __restrict__ pred){
    int o = threadIdx.x;
    __shared__ float co[ODIM];
    float s = 0.0f;
    for (int b=0;b<32;++b) s += copart[b*ODIM + o];
    co[o] = s;
    __syncthreads();
    float acc = head_b[o];
    for (int c=0;c<ODIM;++c) acc = fmaf(head_w[(size_t)o*ODIM + c], co[c], acc);
    pred[o] = acc;
}

extern "C" void kernel_launch(void* const* d_in, const int* in_sizes, int n_in,
                              void* d_out, int out_size, void* d_ws, size_t ws_size,
                              hipStream_t stream)
{
    const float* x      = (const float*)d_in[0];
    const float* hiddens= (const float*)d_in[1];
    const float* W1a=(const float*)d_in[2];  const float* b1a=(const float*)d_in[3];
    const float* W2a=(const float*)d_in[4];  const float* b2a=(const float*)d_in[5];
    const float* W1g=(const float*)d_in[6];  const float* b1g=(const float*)d_in[7];
    const float* W2g=(const float*)d_in[8];  const float* b2g=(const float*)d_in[9];
    const float* w_ih=(const float*)d_in[10]; const float* w_hh=(const float*)d_in[11];
    const float* b_ih=(const float*)d_in[12]; const float* b_hh=(const float*)d_in[13];
    const float* head_w=(const float*)d_in[14]; const float* head_b=(const float*)d_in[15];
    const float* ent=(const float*)d_in[16]; const float* bell=(const float*)d_in[17];
    const int*   stepp=(const int*)d_in[18];
    float* out = (float*)d_out;

    char* wsb = (char*)d_ws;
    size_t off = 0;
    auto carve = [&](size_t bytes)->char*{ char* p = wsb + off; off += (bytes + 63) & ~(size_t)63; return p; };
    ushort_t* combf = (ushort_t*)carve((size_t)1024*768*2);
    ushort_t* hiddf = (ushort_t*)carve((size_t)1024*512*2);
    ushort_t* Wc1f  = (ushort_t*)carve((size_t)256*768*2);
    ushort_t* Wc2f  = (ushort_t*)carve((size_t)256*256*2);
    ushort_t* wihf  = (ushort_t*)carve((size_t)1536*256*2);
    ushort_t* whhf  = (ushort_t*)carve((size_t)1536*512*2);
    ushort_t* H1f   = (ushort_t*)carve((size_t)1024*256*2);
    ushort_t* Of    = (ushort_t*)carve((size_t)1024*256*2);
    float* bc1   = (float*)carve(256*4);
    float* bc2   = (float*)carve(256*4);
    float* wcol  = (float*)carve(1536*4);
    float* OUT   = (float*)carve((size_t)1024*256*4);
    float* tension=(float*)carve(1024*4);
    float* GI    = (float*)carve((size_t)1024*1536*4);
    float* GH    = (float*)carve((size_t)1024*1536*4);
    float* hmix  = (float*)carve((size_t)1024*512*4);
    float* fmean = (float*)carve(8*512*4);
    float* weights=(float*)carve(1024*4);
    float* copart =(float*)carve(32*256*4);

    k_cvt<<<5408, 64, 0, stream>>>(x, hiddens, W1a, W1g, W2a, W2g, w_ih, w_hh,
                                   b1a, b1g, b2a, b2g,
                                   Wc1f, Wc2f, wihf, whhf, combf, hiddf, bc1, bc2, wcol);
    // L1: H1 = relu([x|hiddens] @ [W1a;W1g]^T + bc1), bf16 A-frag out
    k_mm<24,1><<<dim3(8,16), 256, 0, stream>>>(combf, Wc1f, bc1, nullptr, H1f, 256);
    // L2: OUT = H1 @ [W2a|-W2g]^T + (b2a-b2g), f32 out
    k_mm<8,0><<<dim3(8,16), 256, 0, stream>>>(H1f, Wc2f, bc2, OUT, nullptr, 256);
    k_tension_cvt<<<64, 512, 0, stream>>>(OUT, tension, Of);
    // GH: hiddens @ w_hh^T + b_hh
    k_mm<16,0><<<dim3(48,16), 256, 0, stream>>>(hiddf, whhf, b_hh, GH, nullptr, 1536);
    // GI: OUT @ w_ih[:,:256]^T + b_ih  (tension column folded into k_mix via wcol)
    k_mm<8,0><<<dim3(48,16), 256, 0, stream>>>(Of, wihf, b_ih, GI, nullptr, 1536);
    k_mix<<<512, 512, 0, stream>>>(GI, GH, tension, wcol, hiddens, bell, ent, hmix);
    k_fmean<<<8, 512, 0, stream>>>(hmix, fmean);
    k_final_h<<<1024, 512, 0, stream>>>(hmix, fmean, stepp, out + 257);
    k_softmax<<<1, 1024, 0, stream>>>(tension, weights, out + 256);
    k_copart<<<32, 256, 0, stream>>>(OUT, weights, copart);
    k_pred<<<1, 256, 0, stream>>>(copart, head_w, head_b, out);
}

// Round 9
// 160.764 us; speedup vs baseline: 1.6733x; 1.0268x over previous
//
#include <hip/hip_runtime.h>
#include <math.h>

#define NCELLS 1024
#define HID 512
#define ODIM 256
#define NPAIRS 512

typedef __attribute__((ext_vector_type(4))) float f32x4;
typedef __attribute__((ext_vector_type(8))) short short8;
typedef unsigned short ushort_t;

__device__ inline float sigm(float x){ return 1.0f/(1.0f + expf(-x)); }
__device__ inline float tanh3(float x){ return x*fmaf(x*x, -0.33333334f, 1.0f); }
__device__ inline ushort_t f2bf(float f){
    unsigned u = __float_as_uint(f);
    return (ushort_t)((u + 0x7FFFu + ((u>>16)&1u)) >> 16);
}

// ============ K_CVT: build bf16 fragment-order operands ============
__global__ __launch_bounds__(64) void k_cvt(
    const float* __restrict__ x, const float* __restrict__ hiddens,
    const float* __restrict__ W1a, const float* __restrict__ W1g,
    const float* __restrict__ W2a, const float* __restrict__ W2g,
    const float* __restrict__ w_ih, const float* __restrict__ w_hh,
    const float* __restrict__ b1a, const float* __restrict__ b1g,
    const float* __restrict__ b2a, const float* __restrict__ b2g,
    ushort_t* __restrict__ Wc1f, ushort_t* __restrict__ Wc2f,
    ushort_t* __restrict__ wihf, ushort_t* __restrict__ whhf,
    ushort_t* __restrict__ combf, ushort_t* __restrict__ hiddf,
    float* __restrict__ bc1, float* __restrict__ bc2, float* __restrict__ wcol)
{
    const int b = blockIdx.x;
    const int lane = threadIdx.x;
    if (b >= 5376){ // tail: scalar jobs
        int t = (b - 5376)*64 + lane;
        if (t < 256)       bc1[t] = (t<128) ? b1a[t] : b1g[t-128];
        else if (t < 512)  { int i=t-256; bc2[i] = b2a[i] - b2g[i]; }
        else               { int i=t-512; wcol[i] = w_ih[(size_t)i*257 + 256]; }
        return;
    }
    int job, idx, KT; ushort_t* dst;
    if      (b < 384){  job=0; idx=b;      KT=24; dst=Wc1f; }
    else if (b < 512){  job=1; idx=b-384;  KT=8;  dst=Wc2f; }
    else if (b < 1280){ job=2; idx=b-512;  KT=8;  dst=wihf; }
    else if (b < 2816){ job=3; idx=b-1280; KT=16; dst=whhf; }
    else if (b < 4352){ job=4; idx=b-2816; KT=24; dst=combf;}
    else             {  job=5; idx=b-4352; KT=16; dst=hiddf;}
    const int rt = idx / KT, kt = idx % KT;
    const int r  = rt*16 + (lane & 15);
    const int kb = kt*32 + (lane >> 4)*8;
    float v[8];
    if (job == 0){
        const float* s = (r < 128) ? (W1a + (size_t)r*768) : (W1g + (size_t)(r-128)*768);
        #pragma unroll
        for (int j=0;j<8;++j) v[j] = s[kb+j];
    } else if (job == 1){
        if (kb < 128){ const float* s = W2a + (size_t)r*128 + kb;
            #pragma unroll
            for (int j=0;j<8;++j) v[j] = s[j];
        } else { const float* s = W2g + (size_t)r*128 + (kb-128);
            #pragma unroll
            for (int j=0;j<8;++j) v[j] = -s[j];
        }
    } else if (job == 2){
        const float* s = w_ih + (size_t)r*257 + kb;
        #pragma unroll
        for (int j=0;j<8;++j) v[j] = s[j];
    } else if (job == 3){
        const float* s = w_hh + (size_t)r*512 + kb;
        #pragma unroll
        for (int j=0;j<8;++j) v[j] = s[j];
    } else if (job == 4){
        if (kb < 256){
            #pragma unroll
            for (int j=0;j<8;++j) v[j] = x[kb+j];
        } else { const float* s = hiddens + (size_t)r*512 + (kb-256);
            #pragma unroll
            for (int j=0;j<8;++j) v[j] = s[j];
        }
    } else {
        const float* s = hiddens + (size_t)r*512 + kb;
        #pragma unroll
        for (int j=0;j<8;++j) v[j] = s[j];
    }
    short8 o;
    #pragma unroll
    for (int j=0;j<8;++j) o[j] = (short)f2bf(v[j]);
    ((short8*)dst)[(size_t)idx*64 + lane] = o;
}

// ============ MFMA GEMM: C[M x N] = A @ W^T + bias ============
template<int KT, int EPI>
__global__ __launch_bounds__(256) void k_mm(
    const ushort_t* __restrict__ Af, const ushort_t* __restrict__ Bf,
    const float* __restrict__ bias, float* __restrict__ C,
    ushort_t* __restrict__ Cf, int N)
{
    const int lane = threadIdx.x & 63;
    const int w    = threadIdx.x >> 6;
    const int mtile = blockIdx.y*4 + w;
    const int nt0   = blockIdx.x*2;
    const short8* A8 = (const short8*)Af;
    const short8* B8 = (const short8*)Bf;
    f32x4 acc0 = {0.f,0.f,0.f,0.f}, acc1 = {0.f,0.f,0.f,0.f};
    #pragma unroll 4
    for (int kt=0; kt<KT; ++kt){
        short8 a  = A8[((size_t)mtile*KT + kt)*64 + lane];
        short8 b0 = B8[((size_t)nt0*KT + kt)*64 + lane];
        short8 b1 = B8[((size_t)(nt0+1)*KT + kt)*64 + lane];
        acc0 = __builtin_amdgcn_mfma_f32_16x16x32_bf16(a, b0, acc0, 0,0,0);
        acc1 = __builtin_amdgcn_mfma_f32_16x16x32_bf16(a, b1, acc1, 0,0,0);
    }
    if (EPI == 0){
        const int r0 = mtile*16 + (lane>>4)*4;
        const int c0 = nt0*16 + (lane&15);
        const float bb0 = bias[c0], bb1 = bias[c0+16];
        #pragma unroll
        for (int i=0;i<4;++i){
            C[(size_t)(r0+i)*N + c0]    = acc0[i] + bb0;
            C[(size_t)(r0+i)*N + c0+16] = acc1[i] + bb1;
        }
    } else {
        __shared__ float lt[4][16][33];
        const int rr = (lane>>4)*4, cc = lane&15;
        const float bb0 = bias[nt0*16 + cc], bb1 = bias[nt0*16 + 16 + cc];
        #pragma unroll
        for (int i=0;i<4;++i){
            lt[w][rr+i][cc]    = fmaxf(acc0[i] + bb0, 0.f);
            lt[w][rr+i][16+cc] = fmaxf(acc1[i] + bb1, 0.f);
        }
        __syncthreads();
        const int m = lane & 15, kb = (lane>>4)*8;
        short8 o;
        #pragma unroll
        for (int j=0;j<8;++j) o[j] = (short)f2bf(lt[w][m][kb+j]);
        ((short8*)Cf)[((size_t)mtile*gridDim.x + blockIdx.x)*64 + lane] = o;
    }
}

// ============ merged GI/GH GEMM: z=0 -> (A0,B0,bias0,C0,KT0), z=1 -> set 1 ============
__global__ __launch_bounds__(256) void k_mm2(
    const ushort_t* __restrict__ A0, const ushort_t* __restrict__ B0,
    const float* __restrict__ bias0, float* __restrict__ C0, int KT0,
    const ushort_t* __restrict__ A1, const ushort_t* __restrict__ B1,
    const float* __restrict__ bias1, float* __restrict__ C1, int KT1,
    int N)
{
    const ushort_t* Af = A0; const ushort_t* Bf = B0;
    const float* bias = bias0; float* C = C0; int KT = KT0;
    if (blockIdx.z == 1){ Af = A1; Bf = B1; bias = bias1; C = C1; KT = KT1; }
    const int lane = threadIdx.x & 63;
    const int w    = threadIdx.x >> 6;
    const int mtile = blockIdx.y*4 + w;
    const int nt0   = blockIdx.x*2;
    const short8* A8 = (const short8*)Af;
    const short8* B8 = (const short8*)Bf;
    f32x4 acc0 = {0.f,0.f,0.f,0.f}, acc1 = {0.f,0.f,0.f,0.f};
    #pragma unroll 2
    for (int kt=0; kt<KT; ++kt){
        short8 a  = A8[((size_t)mtile*KT + kt)*64 + lane];
        short8 b0 = B8[((size_t)nt0*KT + kt)*64 + lane];
        short8 b1 = B8[((size_t)(nt0+1)*KT + kt)*64 + lane];
        acc0 = __builtin_amdgcn_mfma_f32_16x16x32_bf16(a, b0, acc0, 0,0,0);
        acc1 = __builtin_amdgcn_mfma_f32_16x16x32_bf16(a, b1, acc1, 0,0,0);
    }
    const int r0 = mtile*16 + (lane>>4)*4;
    const int c0 = nt0*16 + (lane&15);
    const float bb0 = bias[c0], bb1 = bias[c0+16];
    #pragma unroll
    for (int i=0;i<4;++i){
        C[(size_t)(r0+i)*N + c0]    = acc0[i] + bb0;
        C[(size_t)(r0+i)*N + c0+16] = acc1[i] + bb1;
    }
}

// ============ tension + OUT -> bf16 A-frag ============
__global__ __launch_bounds__(512) void k_tension_cvt(const float* __restrict__ OUT,
        float* __restrict__ tension, ushort_t* __restrict__ Of)
{
    const int mt = blockIdx.x;
    const int lane = threadIdx.x & 63, wv = threadIdx.x >> 6; // wv = ktile (8)
    const int m = mt*16 + (lane&15);
    const int k = wv*32 + (lane>>4)*8;
    const float* p = OUT + (size_t)m*ODIM + k;
    float4 v0 = *(const float4*)p;
    float4 v1 = *(const float4*)(p+4);
    float s = v0.x*v0.x + v0.y*v0.y + v0.z*v0.z + v0.w*v0.w
            + v1.x*v1.x + v1.y*v1.y + v1.z*v1.z + v1.w*v1.w;
    short8 o;
    o[0]=(short)f2bf(v0.x); o[1]=(short)f2bf(v0.y); o[2]=(short)f2bf(v0.z); o[3]=(short)f2bf(v0.w);
    o[4]=(short)f2bf(v1.x); o[5]=(short)f2bf(v1.y); o[6]=(short)f2bf(v1.z); o[7]=(short)f2bf(v1.w);
    ((short8*)Of)[((size_t)mt*8 + wv)*64 + lane] = o;
    s += __shfl_xor(s, 16); s += __shfl_xor(s, 32);
    __shared__ float red[8][16];
    if (lane < 16) red[wv][lane] = s;
    __syncthreads();
    if (threadIdx.x < 16){
        float t = 0.f;
        #pragma unroll
        for (int q=0;q<8;++q) t += red[q][threadIdx.x];
        tension[mt*16 + threadIdx.x] = t * (1.0f/ODIM);
    }
}

// ============ fused GRU + pair entanglement mixing ============
__global__ __launch_bounds__(512) void k_mix(const float* __restrict__ GI,
        const float* __restrict__ GH, const float* __restrict__ tension,
        const float* __restrict__ wcol, const float* __restrict__ hiddens,
        const float* __restrict__ bell, const float* __restrict__ ent,
        float* __restrict__ hmix)
{
    const int p = blockIdx.x;
    const int tid = threadIdx.x;
    const int lane = tid & 63;
    const int wv = tid >> 6;
    __shared__ __align__(16) float hi[HID], hj[HID];
    __shared__ __align__(16) float colacc[8][HID];
    {
        const int j = tid;
        const float wj0 = wcol[j], wj1 = wcol[512+j], wj2 = wcol[1024+j];
        #pragma unroll
        for (int c01=0; c01<2; ++c01){
            const int cell = 2*p + c01;
            const float tv = tension[cell];
            const float* gi = GI + (size_t)cell*1536;
            const float* gh = GH + (size_t)cell*1536;
            float rg = sigm(gi[j]      + tv*wj0 + gh[j]);
            float zg = sigm(gi[512+j]  + tv*wj1 + gh[512+j]);
            float nn = tanhf(gi[1024+j]+ tv*wj2 + rg*gh[1024+j]);
            float h  = (1.f - zg)*nn + zg*hiddens[(size_t)cell*HID + j];
            (c01 ? hj : hi)[j] = h;
        }
    }
    __syncthreads();
    const float* __restrict__ rot = bell + (size_t)p * HID * HID;
    const float e = 1.0f/(1.0f + expf(-ent[p]));
    const float one_e = 1.0f - e;
    const int c0 = lane<<2, c1 = 256 + (lane<<2);
    float hjr[8];
    #pragma unroll
    for (int k=0;k<4;++k){ hjr[k]=hj[c0+k]; hjr[4+k]=hj[c1+k]; }
    float aj[8] = {};
    #pragma unroll 2
    for (int r = wv; r < HID; r += 32) {
        const float* rp0 = rot + (size_t)r*HID;
        const float* rp1 = rot + (size_t)(r+8)*HID;
        const float* rp2 = rot + (size_t)(r+16)*HID;
        const float* rp3 = rot + (size_t)(r+24)*HID;
        float4 a0 = *(const float4*)(rp0 + c0);
        float4 a1 = *(const float4*)(rp0 + c1);
        float4 b0 = *(const float4*)(rp1 + c0);
        float4 b1 = *(const float4*)(rp1 + c1);
        float4 g0 = *(const float4*)(rp2 + c0);
        float4 g1 = *(const float4*)(rp2 + c1);
        float4 d0 = *(const float4*)(rp3 + c0);
        float4 d1 = *(const float4*)(rp3 + c1);
        float t0[8], t1[8], t2[8], t3[8];
        t0[0]=tanh3(a0.x); t0[1]=tanh3(a0.y); t0[2]=tanh3(a0.z); t0[3]=tanh3(a0.w);
        t0[4]=tanh3(a1.x); t0[5]=tanh3(a1.y); t0[6]=tanh3(a1.z); t0[7]=tanh3(a1.w);
        t1[0]=tanh3(b0.x); t1[1]=tanh3(b0.y); t1[2]=tanh3(b0.z); t1[3]=tanh3(b0.w);
        t1[4]=tanh3(b1.x); t1[5]=tanh3(b1.y); t1[6]=tanh3(b1.z); t1[7]=tanh3(b1.w);
        t2[0]=tanh3(g0.x); t2[1]=tanh3(g0.y); t2[2]=tanh3(g0.z); t2[3]=tanh3(g0.w);
        t2[4]=tanh3(g1.x); t2[5]=tanh3(g1.y); t2[6]=tanh3(g1.z); t2[7]=tanh3(g1.w);
        t3[0]=tanh3(d0.x); t3[1]=tanh3(d0.y); t3[2]=tanh3(d0.z); t3[3]=tanh3(d0.w);
        t3[4]=tanh3(d1.x); t3[5]=tanh3(d1.y); t3[6]=tanh3(d1.z); t3[7]=tanh3(d1.w);
        const float h0 = hi[r], h1 = hi[r+8], h2 = hi[r+16], h3 = hi[r+24];
        float rp_0 = 0.f, rp_1 = 0.f, rp_2 = 0.f, rp_3 = 0.f;
        #pragma unroll
        for (int k=0;k<8;++k){
            rp_0 = fmaf(t0[k], hjr[k], rp_0);
            rp_1 = fmaf(t1[k], hjr[k], rp_1);
            rp_2 = fmaf(t2[k], hjr[k], rp_2);
            rp_3 = fmaf(t3[k], hjr[k], rp_3);
            aj[k] = fmaf(t0[k], h0, fmaf(t1[k], h1, fmaf(t2[k], h2, fmaf(t3[k], h3, aj[k]))));
        }
        #pragma unroll
        for (int m=1;m<64;m<<=1){
            rp_0 += __shfl_xor(rp_0, m);
            rp_1 += __shfl_xor(rp_1, m);
            rp_2 += __shfl_xor(rp_2, m);
            rp_3 += __shfl_xor(rp_3, m);
        }
        if (lane == 0){
            float* dst = hmix + (size_t)(2*p)*HID;
            dst[r]    = one_e*h0 + e*rp_0;
            dst[r+8]  = one_e*h1 + e*rp_1;
            dst[r+16] = one_e*h2 + e*rp_2;
            dst[r+24] = one_e*h3 + e*rp_3;
        }
    }
    *(float4*)&colacc[wv][c0] = make_float4(aj[0],aj[1],aj[2],aj[3]);
    *(float4*)&colacc[wv][c1] = make_float4(aj[4],aj[5],aj[6],aj[7]);
    __syncthreads();
    float s = 0.0f;
    #pragma unroll
    for (int w=0;w<8;++w) s += colacc[w][tid];
    hmix[(size_t)(2*p+1)*HID + tid] = -(one_e*hj[tid] + e*s);
}

// ============ faction mean (32 blocks x 128 thr) ============
__global__ __launch_bounds__(128) void k_fmean(const float* __restrict__ hmix, float* __restrict__ fmean){
    int f = blockIdx.x >> 2;
    int d = (blockIdx.x & 3)*128 + threadIdx.x;
    float s = 0.0f;
    for (int c=0;c<128;++c) s += hmix[(size_t)((f<<7)+c)*HID + d];
    fmean[f*HID + d] = s*(1.0f/128.0f);
}

// ============ faction sync + debate ============
__global__ __launch_bounds__(512) void k_final_h(const float* __restrict__ hmix,
        const float* __restrict__ fmean, const int* __restrict__ stepp, float* __restrict__ hout){
    int cell = blockIdx.x, d = threadIdx.x;
    int f = cell >> 7;
    float v = 0.85f*hmix[(size_t)cell*HID + d] + 0.15f*fmean[f*HID + d];
    if (*stepp > 5 && (cell & 127) < 32){
        float g = 0.0f;
        #pragma unroll
        for (int q=0;q<8;++q) g += fmean[q*HID + d];
        g *= 0.125f;
        v = 0.85f*v + 0.15f*g;
    }
    hout[(size_t)cell*HID + d] = v;
}

// ============ fused softmax + weighted row-sum partials (32 blocks x 256) ============
// Every block redundantly computes softmax(tension) into LDS (tiny), then its
// 32-row copart slice. Block 0 also writes avg_tension.
__global__ __launch_bounds__(256) void k_softcopart(const float* __restrict__ tension,
        const float* __restrict__ OUT, float* __restrict__ copart, float* __restrict__ avg_out)
{
    const int t = threadIdx.x;
    const int lane = t & 63, wv = t >> 6;
    __shared__ float red[4], redb[4], SS[2];
    __shared__ float wts[1024];
    float4 tv = *(const float4*)&tension[t*4];
    float m = fmaxf(fmaxf(tv.x, tv.y), fmaxf(tv.z, tv.w));
    #pragma unroll
    for (int s=1;s<64;s<<=1) m = fmaxf(m, __shfl_xor(m, s));
    if (lane==0) red[wv] = m;
    __syncthreads();
    float M = fmaxf(fmaxf(red[0],red[1]), fmaxf(red[2],red[3]));
    float e0 = expf(tv.x - M), e1 = expf(tv.y - M), e2 = expf(tv.z - M), e3 = expf(tv.w - M);
    float s2 = e0+e1+e2+e3;
    float s3 = tv.x+tv.y+tv.z+tv.w;
    #pragma unroll
    for (int s=1;s<64;s<<=1){ s2 += __shfl_xor(s2,s); s3 += __shfl_xor(s3,s); }
    if (lane==0){ red[wv]=s2; redb[wv]=s3; }
    __syncthreads();
    if (t==0){
        SS[0] = red[0]+red[1]+red[2]+red[3];
        if (blockIdx.x == 0)
            avg_out[0] = (redb[0]+redb[1]+redb[2]+redb[3]) * (1.0f/1024.0f);
    }
    __syncthreads();
    const float inv = 1.0f / SS[0];
    wts[t*4+0] = e0*inv; wts[t*4+1] = e1*inv; wts[t*4+2] = e2*inv; wts[t*4+3] = e3*inv;
    __syncthreads();
    const int b = blockIdx.x;
    float s = 0.0f;
    for (int r = b*32; r < b*32+32; ++r)
        s = fmaf(wts[r], OUT[(size_t)r*ODIM + t], s);
    copart[b*ODIM + t] = s;
}

// ============ head ============
__global__ __launch_bounds__(256) void k_pred(const float* __restrict__ copart,
        const float* __restrict__ head_w, const float* __restrict__ head_b, float* __restrict__ pred){
    int o = threadIdx.x;
    __shared__ float co[ODIM];
    float s = 0.0f;
    for (int b=0;b<32;++b) s += copart[b*ODIM + o];
    co[o] = s;
    __syncthreads();
    float acc = head_b[o];
    for (int c=0;c<ODIM;++c) acc = fmaf(head_w[(size_t)o*ODIM + c], co[c], acc);
    pred[o] = acc;
}

extern "C" void kernel_launch(void* const* d_in, const int* in_sizes, int n_in,
                              void* d_out, int out_size, void* d_ws, size_t ws_size,
                              hipStream_t stream)
{
    const float* x      = (const float*)d_in[0];
    const float* hiddens= (const float*)d_in[1];
    const float* W1a=(const float*)d_in[2];  const float* b1a=(const float*)d_in[3];
    const float* W2a=(const float*)d_in[4];  const float* b2a=(const float*)d_in[5];
    const float* W1g=(const float*)d_in[6];  const float* b1g=(const float*)d_in[7];
    const float* W2g=(const float*)d_in[8];  const float* b2g=(const float*)d_in[9];
    const float* w_ih=(const float*)d_in[10]; const float* w_hh=(const float*)d_in[11];
    const float* b_ih=(const float*)d_in[12]; const float* b_hh=(const float*)d_in[13];
    const float* head_w=(const float*)d_in[14]; const float* head_b=(const float*)d_in[15];
    const float* ent=(const float*)d_in[16]; const float* bell=(const float*)d_in[17];
    const int*   stepp=(const int*)d_in[18];
    float* out = (float*)d_out;

    char* wsb = (char*)d_ws;
    size_t off = 0;
    auto carve = [&](size_t bytes)->char*{ char* p = wsb + off; off += (bytes + 63) & ~(size_t)63; return p; };
    ushort_t* combf = (ushort_t*)carve((size_t)1024*768*2);
    ushort_t* hiddf = (ushort_t*)carve((size_t)1024*512*2);
    ushort_t* Wc1f  = (ushort_t*)carve((size_t)256*768*2);
    ushort_t* Wc2f  = (ushort_t*)carve((size_t)256*256*2);
    ushort_t* wihf  = (ushort_t*)carve((size_t)1536*256*2);
    ushort_t* whhf  = (ushort_t*)carve((size_t)1536*512*2);
    ushort_t* H1f   = (ushort_t*)carve((size_t)1024*256*2);
    ushort_t* Of    = (ushort_t*)carve((size_t)1024*256*2);
    float* bc1   = (float*)carve(256*4);
    float* bc2   = (float*)carve(256*4);
    float* wcol  = (float*)carve(1536*4);
    float* OUT   = (float*)carve((size_t)1024*256*4);
    float* tension=(float*)carve(1024*4);
    float* GI    = (float*)carve((size_t)1024*1536*4);
    float* GH    = (float*)carve((size_t)1024*1536*4);
    float* hmix  = (float*)carve((size_t)1024*512*4);
    float* fmean = (float*)carve(8*512*4);
    float* copart =(float*)carve(32*256*4);

    k_cvt<<<5408, 64, 0, stream>>>(x, hiddens, W1a, W1g, W2a, W2g, w_ih, w_hh,
                                   b1a, b1g, b2a, b2g,
                                   Wc1f, Wc2f, wihf, whhf, combf, hiddf, bc1, bc2, wcol);
    // L1: H1 = relu([x|hiddens] @ [W1a;W1g]^T + bc1), bf16 A-frag out
    k_mm<24,1><<<dim3(8,16), 256, 0, stream>>>(combf, Wc1f, bc1, nullptr, H1f, 256);
    // L2: OUT = H1 @ [W2a|-W2g]^T + (b2a-b2g), f32 out
    k_mm<8,0><<<dim3(8,16), 256, 0, stream>>>(H1f, Wc2f, bc2, OUT, nullptr, 256);
    k_tension_cvt<<<64, 512, 0, stream>>>(OUT, tension, Of);
    // GH (z=0): hiddens @ w_hh^T + b_hh ; GI (z=1): OUT @ w_ih[:,:256]^T + b_ih
    k_mm2<<<dim3(48,16,2), 256, 0, stream>>>(hiddf, whhf, b_hh, GH, 16,
                                             Of,    wihf, b_ih, GI, 8, 1536);
    k_mix<<<512, 512, 0, stream>>>(GI, GH, tension, wcol, hiddens, bell, ent, hmix);
    k_fmean<<<32, 128, 0, stream>>>(hmix, fmean);
    k_final_h<<<1024, 512, 0, stream>>>(hmix, fmean, stepp, out + 257);
    k_softcopart<<<32, 256, 0, stream>>>(tension, OUT, copart, out + 256);
    k_pred<<<1, 256, 0, stream>>>(copart, head_w, head_b, out);
}